// Round 17
// baseline (2915.606 us; speedup 1.0000x reference)
//
#include <hip/hip_runtime.h>
#include <hip/hip_bf16.h>
#include <stdint.h>

// EvolvedLoopLinear: out[b,j] = sum_i x[b,i]*W[j,i] + b[j]
// M=8192, N=4096, K=4096. fp32 in/out, bf16 MFMA compute.
// Round 17: producer/consumer wave STAGGER. 8 waves (2Mx4N, 128x64 each),
// two groups with one wave of each per SIMD (grp = (wid^(wid>>2))&1 -- a
// split that pairs G0+G1 on every SIMD under either wid%4 or wid>>1
// wave->SIMD mapping). Per BK=32 tile, 2 barrier segments:
//   segA: G0 reads tile T frags (12 ds_read) | G1 MFMAs tile T-1 (32)
//   segB: G0 MFMAs tile T            | G1 reads tile T
// => every SIMD always has one wave on the DS port and one feeding the
// MFMA pipe (the overlap lockstep structures forbid; r16 proved partial
// overlap is real but paid 33% extra LDS traffic -- this keeps 8-wave
// minimal traffic). The stagger gives the 1-phase read->MFMA lag with NO
// extra register liveness (one 48-reg frag set per wave, dies when the
// next is born). 4 x 32KB buffers, distance-2 stage (A-half segA, B-half
// segB), counted vmcnt(4), 2 barriers/tile (256 total, = champion).
// LDS layout/staging = r16's HW-verified 0-conflict paired-row formulas.

typedef __bf16 bf16_t;
typedef __bf16 bf16x8 __attribute__((ext_vector_type(8)));
typedef float  f32x4  __attribute__((ext_vector_type(4)));

#define M_DIM 8192
#define N_DIM 4096
#define K_DIM 4096
#define NT    (K_DIM / 32)   // 128 K-tiles of BK=32
#define BUFE  16384          // elements/buffer (32 KB): A 8192 | B 8192

#define GLD16(gp, lp) __builtin_amdgcn_global_load_lds(                    \
    (const __attribute__((address_space(1))) void*)(gp),                   \
    (__attribute__((address_space(3))) void*)(lp), 16, 0, 0)

#define MFMA(a, b, c) __builtin_amdgcn_mfma_f32_16x16x32_bf16((a), (b), (c), 0, 0, 0)

#define FENCE() asm volatile("" ::: "memory")

// ---------------- fp32 -> bf16 convert (vectorized, grid-stride) -----------
__global__ void __launch_bounds__(256) cvt_f32_bf16(
    const float* __restrict__ in, bf16_t* __restrict__ out, long n8)
{
    long i0 = (long)blockIdx.x * blockDim.x + threadIdx.x;
    long stride = (long)gridDim.x * blockDim.x;
    for (long i = i0; i < n8; i += stride) {
        const float4* p = (const float4*)(in + i * 8);
        float4 a = p[0];
        float4 b = p[1];
        bf16x8 o;
        o[0] = (bf16_t)a.x; o[1] = (bf16_t)a.y; o[2] = (bf16_t)a.z; o[3] = (bf16_t)a.w;
        o[4] = (bf16_t)b.x; o[5] = (bf16_t)b.y; o[6] = (bf16_t)b.z; o[7] = (bf16_t)b.w;
        *(bf16x8*)(out + i * 8) = o;
    }
}

// ---------------- 256x256 bf16 GEMM, staggered wave groups, BK=32 ----------
// Buffer q (16384 el): A (256 rows, paired-row [128][64]) @ q*BUFE,
//                      B (256 rows, paired-row [128][64]) @ +8192.
// Paired-row: row r,k -> ldsrow r>>1, off (r&1)*32+k; 16B-chunk slot =
// chunk ^ (ldsrow&7)  [r16 formulas, HW-verified 0 conflicts, refcheck'd].
__global__ void __launch_bounds__(512, 1) gemm_256_st(
    const bf16_t* __restrict__ A, const bf16_t* __restrict__ B,
    const float* __restrict__ bias, float* __restrict__ C)
{
    __shared__ bf16_t sm[4 * BUFE];   // 128 KiB

    // XCD-aware bijective swizzle (gridDim = 512, divisible by 8)
    const int nwg = gridDim.x;
    const int bid = blockIdx.x;
    const int cpx = nwg >> 3;
    const int swz = (bid & 7) * cpx + (bid >> 3);
    const int NBN = N_DIM / 256;                       // 16
    const long blockM = (long)(swz / NBN) * 256;
    const long blockN = (long)(swz % NBN) * 256;

    const int t    = threadIdx.x;
    const int lane = t & 63;
    const int wid  = t >> 6;        // 8 waves: 2 (M) x 4 (N)
    const int wr   = wid >> 2;      // 0..1 -> 128 rows each
    const int wc   = wid & 3;       // 0..3 -> 64 cols each
    const int l15  = lane & 15;
    const int lk   = lane >> 4;     // 0..3
    // group: one G0 + one G1 wave per SIMD under wid%4 OR wid>>1 mapping
    const int grp  = __builtin_amdgcn_readfirstlane((wid ^ (wid >> 2)) & 1);

    // staging [r16 verbatim]: chunk c_i of a region: ldsrow = c_i>>3,
    // slot = c_i&7, global chunk g = slot^(ldsrow&7), global row =
    // 2*ldsrow + (g>>2), k-chunk = (g&3)*8. Thread t covers chunks t and
    // t+512 (the +512 chunk is exactly +128 global rows, same k-chunk).
    const int sr = t >> 3;
    const int c  = (t & 7) ^ (sr & 7);
    const int grow = 2 * sr + (c >> 2);
    const int kc8  = (c & 3) * 8;
    const bf16_t* gA = A + (blockM + grow) * (long)K_DIM + kc8;
    const bf16_t* gB = B + (blockN + grow) * (long)K_DIM + kc8;
    const int dstT = t * 8;         // chunk t dest (el); chunk t+512: +4096

    // fragment reads [r16 formulas]: frag f: row = wr*128 + f*16 + l15 ->
    // ldsrow = wr*64 + f*8 + (l15>>1); slot = ((l15&1)*4 + lk) ^ (l15>>1).
    const int slotA = (((((l15 & 1) << 2) + lk) ^ (l15 >> 1)) << 3);
    const int aBase = (wr * 64 + (l15 >> 1)) * 64 + slotA;          // +f*512
    const int bBase = 8192 + (wc * 32 + (l15 >> 1)) * 64 + slotA;   // +n*512

    f32x4 acc[8][4] = {};
    bf16x8 a[8], b[4];

#define STAGE_AH(q, tk) do {                                               \
    bf16_t* _l = (bf16_t*)sm + (q) * BUFE + dstT;                          \
    GLD16(gA + (long)(tk) * 32,                _l);                        \
    GLD16(gA + (long)(tk) * 32 + 128L * K_DIM, _l + 4096); } while (0)

#define STAGE_BH(q, tk) do {                                               \
    bf16_t* _l = (bf16_t*)sm + (q) * BUFE + 8192 + dstT;                   \
    GLD16(gB + (long)(tk) * 32,                _l);                        \
    GLD16(gB + (long)(tk) * 32 + 128L * K_DIM, _l + 4096); } while (0)

#define READ_ALL(s) do {                                                   \
    _Pragma("unroll") for (int n = 0; n < 4; ++n)                          \
        b[n] = *(const bf16x8*)((s) + bBase + n * 512);                    \
    _Pragma("unroll") for (int m = 0; m < 8; ++m)                          \
        a[m] = *(const bf16x8*)((s) + aBase + m * 512); } while (0)

#define MFMA_ALL() do {                                                    \
    __builtin_amdgcn_s_setprio(1);                                         \
    _Pragma("unroll") for (int m = 0; m < 8; ++m)                          \
    _Pragma("unroll") for (int n = 0; n < 4; ++n)                          \
        acc[m][n] = MFMA(a[m], b[n], acc[m][n]);                           \
    __builtin_amdgcn_s_setprio(0); } while (0)

    // prologue: tiles 0,1 fully staged (fence-pinned order); vmcnt(4)
    // leaves tile1's 4 in flight with tile0 resident.
    STAGE_AH(0, 0); STAGE_BH(0, 0);
    FENCE();
    STAGE_AH(1, 1); STAGE_BH(1, 1);
    FENCE();
    asm volatile("s_waitcnt vmcnt(4)" ::: "memory");
    __builtin_amdgcn_sched_barrier(0);
    __builtin_amdgcn_s_barrier();
    FENCE();

    for (int tk = 0; tk < NT; ++tk) {
        const bf16_t* s = (const bf16_t*)sm + (tk & 3) * BUFE;
        const int q2 = (tk + 2) & 3;
        const bool full = (tk + 2 < NT);

        // ===== segment A: stage A-half(T+2) | G0 reads T, G1 MFMAs T-1 ==
        if (full) STAGE_AH(q2, tk + 2);
        FENCE();
        if (grp == 0) {
            READ_ALL(s);
        } else if (tk > 0) {
            MFMA_ALL();
        }
        FENCE();
        __builtin_amdgcn_s_barrier();
        FENCE();

        // ===== segment B: stage B-half(T+2) | G0 MFMAs T, G1 reads T ====
        if (full) STAGE_BH(q2, tk + 2);
        FENCE();
        if (grp == 0) {
            MFMA_ALL();
        } else {
            READ_ALL(s);
        }
        // counted drain: T+1's 4 loads land; T+2's 4 stay in flight
        if (tk < NT - 2) asm volatile("s_waitcnt vmcnt(4)" ::: "memory");
        else             asm volatile("s_waitcnt vmcnt(0)" ::: "memory");
        __builtin_amdgcn_sched_barrier(0);
        __builtin_amdgcn_s_barrier();
        FENCE();
    }

    // G1 owes the MFMA for tile NT-1 (read in its last segB)
    if (grp != 0) MFMA_ALL();

#undef STAGE_AH
#undef STAGE_BH

    // epilogue: C/D layout col = lane&15, row = (lane>>4)*4 + j
    const long cb = blockN + wc * 64;
    float bv[4];
    long  cn[4];
#pragma unroll
    for (int n = 0; n < 4; ++n) {
        cn[n] = cb + n * 16 + l15;
        bv[n] = bias[cn[n]];
    }
#pragma unroll
    for (int m = 0; m < 8; ++m) {
        const long r0 = blockM + wr * 128 + m * 16 + lk * 4;
#pragma unroll
        for (int n = 0; n < 4; ++n)
#pragma unroll
            for (int j = 0; j < 4; ++j)
                C[(r0 + j) * (long)N_DIM + cn[n]] = acc[m][n][j] + bv[n];
    }
}

// ---------------- fp32 fallback (only if ws too small) ---------------------
__global__ void __launch_bounds__(256) gemm_f32_fallback(
    const float* __restrict__ A, const float* __restrict__ W,
    const float* __restrict__ bias, float* __restrict__ C)
{
    __shared__ float sA[64][17];
    __shared__ float sB[64][17];
    const int bm = blockIdx.y, bn = blockIdx.x;
    const int t = threadIdx.x;
    const int tx = t & 15, ty = t >> 4;
    const long row0 = (long)bm * 64, col0 = (long)bn * 64;
    float acc[4][4] = {};
    for (int kt = 0; kt < K_DIM; kt += 16) {
        const int r = t >> 2, c = (t & 3) * 4;
        float4 a4 = *(const float4*)&A[(row0 + r) * K_DIM + kt + c];
        float4 b4 = *(const float4*)&W[(col0 + r) * K_DIM + kt + c];
        sA[r][c] = a4.x; sA[r][c + 1] = a4.y; sA[r][c + 2] = a4.z; sA[r][c + 3] = a4.w;
        sB[r][c] = b4.x; sB[r][c + 1] = b4.y; sB[r][c + 2] = b4.z; sB[r][c + 3] = b4.w;
        __syncthreads();
#pragma unroll
        for (int kk = 0; kk < 16; ++kk) {
            float av[4], bv[4];
#pragma unroll
            for (int i = 0; i < 4; ++i) av[i] = sA[ty * 4 + i][kk];
#pragma unroll
            for (int j = 0; j < 4; ++j) bv[j] = sB[tx * 4 + j][kk];
#pragma unroll
            for (int i = 0; i < 4; ++i)
#pragma unroll
                for (int j = 0; j < 4; ++j) acc[i][j] += av[i] * bv[j];
        }
        __syncthreads();
    }
#pragma unroll
    for (int i = 0; i < 4; ++i)
#pragma unroll
        for (int j = 0; j < 4; ++j)
            C[(row0 + ty * 4 + i) * N_DIM + col0 + tx * 4 + j] =
                acc[i][j] + bias[col0 + tx * 4 + j];
}

extern "C" void kernel_launch(void* const* d_in, const int* in_sizes, int n_in,
                              void* d_out, int out_size, void* d_ws, size_t ws_size,
                              hipStream_t stream)
{
    const float* x = (const float*)d_in[0];   // [8192, 4096]
    const float* W = (const float*)d_in[1];   // [4096, 4096]
    const float* b = (const float*)d_in[2];   // [4096]
    float* out = (float*)d_out;               // [8192, 4096] fp32

    const long xe = (long)M_DIM * K_DIM;
    const long we = (long)N_DIM * K_DIM;
    const size_t need = (size_t)(xe + we) * sizeof(bf16_t);  // ~96 MiB

    if (ws_size >= need) {
        bf16_t* xb = (bf16_t*)d_ws;
        bf16_t* wb = xb + xe;
        cvt_f32_bf16<<<2048, 256, 0, stream>>>(x, xb, xe / 8);
        cvt_f32_bf16<<<1024, 256, 0, stream>>>(W, wb, we / 8);
        gemm_256_st<<<(M_DIM / 256) * (N_DIM / 256), 512, 0, stream>>>(xb, wb, b, out);
    } else {
        dim3 grid(N_DIM / 64, M_DIM / 64);
        gemm_f32_fallback<<<grid, 256, 0, stream>>>(x, W, b, out);
    }
}